// Round 4
// baseline (1490.582 us; speedup 1.0000x reference)
//
#include <hip/hip_runtime.h>

typedef float v2f __attribute__((ext_vector_type(2)));

#define BB 16
#define CC 64
#define NN 4096   // H*W
#define MM 1024   // H*W/4

__device__ __forceinline__ unsigned bf16_rne(float v) {
    unsigned u = __float_as_uint(v);
    return (u + 0x7fffu + ((u >> 16) & 1u)) >> 16;
}
__device__ __forceinline__ unsigned pack_bf16(float a, float b) {
    return bf16_rne(a) | (bf16_rne(b) << 16);
}
__device__ __forceinline__ v2f unpack_bf16(unsigned u) {
    v2f r;
    r.x = __uint_as_float(u << 16);
    r.y = __uint_as_float(u & 0xffff0000u);
    return r;
}

// ---------------------------------------------------------------------------
// Kernel 1: projections + fused 2x2 maxpool, z-split for occupancy.
//   z=0: theta(8) + phi(8) outputs;  z=1: g(32) outputs (stored bf16-packed).
// 128 threads, 2 px/thread (256 px = 4 image rows/block); 512 blocks total.
// Vertical pool partner = lane^32 (lanes 0-31 even row, 32-63 odd row).
// ---------------------------------------------------------------------------
__global__ __launch_bounds__(128, 4) void proj_kernel(
    const float* __restrict__ x,      // [B][C][N]
    const float* __restrict__ w_th,   // [8][64]
    const float* __restrict__ w_ph,   // [8][64]
    const float* __restrict__ w_g,    // [32][64]
    float* __restrict__ theta,        // [B][N][8]
    float* __restrict__ phi,          // [B][M][8]
    unsigned* __restrict__ gpk)       // [B][M][16] bf16 channel-pairs
{
    __shared__ float wlds[64 * 32];   // z0 uses [64][16], z1 [64][32]

    const int b   = blockIdx.y;
    const int blk = blockIdx.x;
    const int z   = blockIdx.z;
    const int t   = threadIdx.x;

    if (z == 0) {
        for (int i = t; i < 1024; i += 128) {       // [c][o], o<8 th, o<16 ph
            int c = i >> 4, o = i & 15;
            wlds[i] = (o < 8) ? w_th[o * 64 + c] : w_ph[(o - 8) * 64 + c];
        }
    } else {
        for (int i = t; i < 2048; i += 128) {       // [c][o]
            int c = i >> 5, o = i & 31;
            wlds[i] = w_g[o * 64 + c];
        }
    }
    __syncthreads();

    const float2* x2 = (const float2*)(x + (size_t)b * CC * NN);
    const int p2 = blk * 128 + t;                   // float2 index in plane
    const int l = t & 63, w = t >> 6;
    const int m = (blk * 2 + w) * 32 + (l & 31);    // pooled index (l<32 lanes)

    if (z == 0) {
        float th0[8], th1[8], ph0[8], ph1[8];
#pragma unroll
        for (int i = 0; i < 8; i++) { th0[i]=th1[i]=ph0[i]=ph1[i]=0.f; }
#pragma unroll 4
        for (int c = 0; c < 64; c++) {
            float2 xv = x2[c * (NN / 2) + p2];
            const float4* w4 = (const float4*)&wlds[c * 16];
            float4 wv[4];
#pragma unroll
            for (int j = 0; j < 4; j++) wv[j] = w4[j];
            const float* wf = (const float*)wv;
#pragma unroll
            for (int o = 0; o < 8; o++) {
                th0[o] = fmaf(wf[o], xv.x, th0[o]);
                th1[o] = fmaf(wf[o], xv.y, th1[o]);
                ph0[o] = fmaf(wf[8 + o], xv.x, ph0[o]);
                ph1[o] = fmaf(wf[8 + o], xv.y, ph1[o]);
            }
        }
        // theta store: pixels 2*p2, 2*p2+1 -> 64 contiguous bytes
        float4* tw = (float4*)(theta + ((size_t)b * NN + 2 * p2) * 8);
        tw[0] = make_float4(th0[0], th0[1], th0[2], th0[3]);
        tw[1] = make_float4(th0[4], th0[5], th0[6], th0[7]);
        tw[2] = make_float4(th1[0], th1[1], th1[2], th1[3]);
        tw[3] = make_float4(th1[4], th1[5], th1[6], th1[7]);
        // phi maxpool + store
        float phm[8];
#pragma unroll
        for (int i = 0; i < 8; i++) phm[i] = fmaxf(ph0[i], ph1[i]);
#pragma unroll
        for (int i = 0; i < 8; i++) phm[i] = fmaxf(phm[i], __shfl_xor(phm[i], 32));
        if (l < 32) {
            float4* pw = (float4*)(phi + ((size_t)b * MM + m) * 8);
            pw[0] = make_float4(phm[0], phm[1], phm[2], phm[3]);
            pw[1] = make_float4(phm[4], phm[5], phm[6], phm[7]);
        }
    } else {
        float gg0[32], gg1[32];
#pragma unroll
        for (int i = 0; i < 32; i++) { gg0[i] = gg1[i] = 0.f; }
#pragma unroll 4
        for (int c = 0; c < 64; c++) {
            float2 xv = x2[c * (NN / 2) + p2];
            const float4* w4 = (const float4*)&wlds[c * 32];
            float4 wv[8];
#pragma unroll
            for (int j = 0; j < 8; j++) wv[j] = w4[j];
            const float* wf = (const float*)wv;
#pragma unroll
            for (int o = 0; o < 32; o++) {
                gg0[o] = fmaf(wf[o], xv.x, gg0[o]);
                gg1[o] = fmaf(wf[o], xv.y, gg1[o]);
            }
        }
        float ggm[32];
#pragma unroll
        for (int i = 0; i < 32; i++) ggm[i] = fmaxf(gg0[i], gg1[i]);
#pragma unroll
        for (int i = 0; i < 32; i++) ggm[i] = fmaxf(ggm[i], __shfl_xor(ggm[i], 32));
        if (l < 32) {
            unsigned up[16];
#pragma unroll
            for (int k = 0; k < 16; k++) up[k] = pack_bf16(ggm[2*k], ggm[2*k+1]);
            uint4* gw = (uint4*)(gpk + ((size_t)b * MM + m) * 16);
#pragma unroll
            for (int j = 0; j < 4; j++)
                gw[j] = make_uint4(up[4*j], up[4*j+1], up[4*j+2], up[4*j+3]);
        }
    }
}

// ---------------------------------------------------------------------------
// Kernel 2: flash-style attention over an M-chunk, 4 pixels/thread.
// 64-row LDS tiles: phi fp32 (2 KB) + g bf16-packed (4 KB) = 6 KB ->
// 4 blocks/CU, 16 waves/CU. Inner loop: 6 ds_read_b128 + 32 score-fma +
// 4 exp + 16 unpack + 64 v_pk_fma_f32 (via __builtin_elementwise_fma).
// Partials written bf16-pair-packed, denom fp32.
// No max pass: scores ~N(0,2.8^2); fp32 exp overflows only past s=88.
// ---------------------------------------------------------------------------
__global__ __launch_bounds__(256, 4) void attn_kernel(
    const float* __restrict__ theta,    // [B][N][8]
    const float* __restrict__ phi,      // [B][M][8]
    const unsigned* __restrict__ gpk,   // [B][M][16]
    unsigned* __restrict__ pacc,        // [B][nchunk][17][N] (16 pk + den)
    int nchunk)
{
    __shared__ float4 ph4[128];     // 64 m-rows x 8 fp32
    __shared__ uint4  gl4[256];     // 64 m-rows x 16 packed bf16-pairs

    const int b     = blockIdx.z;
    const int chunk = blockIdx.y;
    const int blk   = blockIdx.x;
    const int t     = threadIdx.x;
    const int nb    = blk * 1024 + t;     // pixel 0 of this thread's 4
    const int mc    = MM / nchunk;
    const int mbase = chunk * mc;

    float4 thA[4], thB[4];
#pragma unroll
    for (int p = 0; p < 4; p++) {
        const float4* tp = (const float4*)(theta + ((size_t)b * NN + nb + p * 256) * 8);
        thA[p] = tp[0]; thB[p] = tp[1];
    }

    v2f acc[4][16];
#pragma unroll
    for (int p = 0; p < 4; p++)
#pragma unroll
        for (int k = 0; k < 16; k++) acc[p][k] = (v2f)(0.f);
    float den[4] = {0.f, 0.f, 0.f, 0.f};

    for (int mt = 0; mt < mc; mt += 64) {
        const int base = mbase + mt;
        if (t < 128)
            ph4[t] = ((const float4*)(phi + ((size_t)b * MM + base) * 8))[t];
        gl4[t] = ((const uint4*)(gpk + ((size_t)b * MM + base) * 16))[t];
        __syncthreads();

#pragma unroll 2
        for (int mm = 0; mm < 64; mm++) {
            float4 p0 = ph4[2 * mm], p1 = ph4[2 * mm + 1];
            v2f e2[4];
#pragma unroll
            for (int p = 0; p < 4; p++) {
                float s = thA[p].x * p0.x;
                s = fmaf(thA[p].y, p0.y, s); s = fmaf(thA[p].z, p0.z, s);
                s = fmaf(thA[p].w, p0.w, s); s = fmaf(thB[p].x, p1.x, s);
                s = fmaf(thB[p].y, p1.y, s); s = fmaf(thB[p].z, p1.z, s);
                s = fmaf(thB[p].w, p1.w, s);
                float e = __expf(s);
                den[p] += e;
                e2[p].x = e; e2[p].y = e;
            }
#pragma unroll
            for (int j2 = 0; j2 < 4; j2++) {
                uint4 gq = gl4[mm * 4 + j2];
                unsigned uu[4] = {gq.x, gq.y, gq.z, gq.w};
#pragma unroll
                for (int w = 0; w < 4; w++) {
                    v2f gp = unpack_bf16(uu[w]);
                    int k = j2 * 4 + w;
                    acc[0][k] = __builtin_elementwise_fma(gp, e2[0], acc[0][k]);
                    acc[1][k] = __builtin_elementwise_fma(gp, e2[1], acc[1][k]);
                    acc[2][k] = __builtin_elementwise_fma(gp, e2[2], acc[2][k]);
                    acc[3][k] = __builtin_elementwise_fma(gp, e2[3], acc[3][k]);
                }
            }
        }
        __syncthreads();
    }

    unsigned* pb = pacc + (size_t)(b * nchunk + chunk) * 17 * NN;
#pragma unroll
    for (int p = 0; p < 4; p++) {
        const int n = nb + p * 256;
#pragma unroll
        for (int k = 0; k < 16; k++)
            pb[(size_t)k * NN + n] = pack_bf16(acc[p][k].x, acc[p][k].y);
        pb[(size_t)16 * NN + n] = __float_as_uint(den[p]);
    }
}

// ---------------------------------------------------------------------------
// Kernel 3: combine chunk partials (packed bf16 pairs), normalize, w_o
// projection via wave-uniform scalar loads + pk-fma, gamma + residual.
// 1 px/thread, 256 blocks x 4 waves.
// ---------------------------------------------------------------------------
__global__ __launch_bounds__(256, 4) void reduce_kernel(
    const unsigned* __restrict__ pacc,  // [B][nchunk][17][N]
    const float* __restrict__ w_o,      // [64][32]
    const float* __restrict__ gamma_p,
    const float* __restrict__ x,        // [B][C][N]
    float* __restrict__ out,            // [B][C][N]
    int nchunk)
{
    const int b = blockIdx.y;
    const int t = threadIdx.x;
    const int n = blockIdx.x * 256 + t;

    v2f ov[16];
#pragma unroll
    for (int k = 0; k < 16; k++) ov[k] = (v2f)(0.f);
    float den = 0.f;

    for (int ch = 0; ch < nchunk; ch++) {
        const unsigned* pb = pacc + (size_t)(b * nchunk + ch) * 17 * NN + n;
#pragma unroll
        for (int k = 0; k < 16; k++) ov[k] += unpack_bf16(pb[(size_t)k * NN]);
        den += __uint_as_float(pb[(size_t)16 * NN]);
    }
    const float inv = 1.f / den;
    v2f inv2; inv2.x = inv; inv2.y = inv;
#pragma unroll
    for (int k = 0; k < 16; k++) ov[k] *= inv2;

    const float gamma = gamma_p[0];
#pragma unroll 4
    for (int co = 0; co < 64; co++) {
        const v2f* wrow = (const v2f*)(w_o + co * 32);   // uniform -> s_load
        v2f s2 = (v2f)(0.f);
#pragma unroll
        for (int k = 0; k < 16; k++)
            s2 = __builtin_elementwise_fma(wrow[k], ov[k], s2);
        float v = s2.x + s2.y;
        size_t oi = ((size_t)b * CC + co) * NN + n;
        out[oi] = fmaf(gamma, v, x[oi]);
    }
}

extern "C" void kernel_launch(void* const* d_in, const int* in_sizes, int n_in,
                              void* d_out, int out_size, void* d_ws, size_t ws_size,
                              hipStream_t stream) {
    const float* x       = (const float*)d_in[0];
    const float* w_theta = (const float*)d_in[1];
    const float* w_phi   = (const float*)d_in[2];
    const float* w_g     = (const float*)d_in[3];
    const float* w_o     = (const float*)d_in[4];
    const float* gamma   = (const float*)d_in[5];
    float* out = (float*)d_out;

    // workspace: theta [B][N][8] f32, phi [B][M][8] f32,
    //            gpk [B][M][16] u32, pacc [B][nchunk][17][N] u32
    float*    theta_ws = (float*)d_ws;
    float*    phi_ws   = theta_ws + (size_t)BB * NN * 8;    // 524288 f
    unsigned* gpk_ws   = (unsigned*)(phi_ws + (size_t)BB * MM * 8);  // 131072 f
    unsigned* pacc     = gpk_ws + (size_t)BB * MM * 16;     // 262144 u
    const size_t base_w = (size_t)BB * NN * 8 + (size_t)BB * MM * 8
                        + (size_t)BB * MM * 16;             // 4-byte words

    int nchunk = 16;  // M-split: 1024 attn blocks (4/CU, 16 waves/CU)
    while (nchunk > 1 &&
           (base_w + (size_t)BB * nchunk * 17 * NN) * 4 > ws_size)
        nchunk >>= 1;

    proj_kernel<<<dim3(16, BB, 2), 128, 0, stream>>>(
        x, w_theta, w_phi, w_g, theta_ws, phi_ws, gpk_ws);

    attn_kernel<<<dim3(NN / 1024, nchunk, BB), 256, 0, stream>>>(
        theta_ws, phi_ws, gpk_ws, pacc, nchunk);

    reduce_kernel<<<dim3(NN / 256, BB), 256, 0, stream>>>(
        pacc, w_o, gamma, x, out, nchunk);
}

// Round 5
// 201.053 us; speedup vs baseline: 7.4139x; 7.4139x over previous
//
#include <hip/hip_runtime.h>

typedef float v2f __attribute__((ext_vector_type(2)));

#define BB 16
#define CC 64
#define NN 4096   // H*W
#define MM 1024   // H*W/4

__device__ __forceinline__ unsigned bf16_rne(float v) {
    unsigned u = __float_as_uint(v);
    return (u + 0x7fffu + ((u >> 16) & 1u)) >> 16;
}
__device__ __forceinline__ unsigned pack_bf16(float a, float b) {
    return bf16_rne(a) | (bf16_rne(b) << 16);
}
__device__ __forceinline__ v2f unpack_bf16(unsigned u) {
    v2f r;
    r.x = __uint_as_float(u << 16);
    r.y = __uint_as_float(u & 0xffff0000u);
    return r;
}

// ---------------------------------------------------------------------------
// Kernel 1: projections + fused 2x2 maxpool, z-split for occupancy.
//   z=0: theta(8) + phi(8) outputs;  z=1: g(32) outputs (stored bf16-packed).
// 128 threads, 2 px/thread (256 px = 4 image rows/block); 512 blocks total.
// Vertical pool partner = lane^32 (lanes 0-31 even row, 32-63 odd row).
// ---------------------------------------------------------------------------
__global__ __launch_bounds__(128, 4) void proj_kernel(
    const float* __restrict__ x,      // [B][C][N]
    const float* __restrict__ w_th,   // [8][64]
    const float* __restrict__ w_ph,   // [8][64]
    const float* __restrict__ w_g,    // [32][64]
    float* __restrict__ theta,        // [B][N][8]
    float* __restrict__ phi,          // [B][M][8]
    unsigned* __restrict__ gpk)       // [B][M][16] bf16 channel-pairs
{
    __shared__ float wlds[64 * 32];   // z0 uses [64][16], z1 [64][32]

    const int b   = blockIdx.y;
    const int blk = blockIdx.x;
    const int z   = blockIdx.z;
    const int t   = threadIdx.x;

    if (z == 0) {
        for (int i = t; i < 1024; i += 128) {       // [c][o], o<8 th, o<16 ph
            int c = i >> 4, o = i & 15;
            wlds[i] = (o < 8) ? w_th[o * 64 + c] : w_ph[(o - 8) * 64 + c];
        }
    } else {
        for (int i = t; i < 2048; i += 128) {       // [c][o]
            int c = i >> 5, o = i & 31;
            wlds[i] = w_g[o * 64 + c];
        }
    }
    __syncthreads();

    const float2* x2 = (const float2*)(x + (size_t)b * CC * NN);
    const int p2 = blk * 128 + t;                   // float2 index in plane
    const int l = t & 63, w = t >> 6;
    const int m = (blk * 2 + w) * 32 + (l & 31);    // pooled index (l<32 lanes)

    if (z == 0) {
        float th0[8], th1[8], ph0[8], ph1[8];
#pragma unroll
        for (int i = 0; i < 8; i++) { th0[i]=th1[i]=ph0[i]=ph1[i]=0.f; }
#pragma unroll 4
        for (int c = 0; c < 64; c++) {
            float2 xv = x2[c * (NN / 2) + p2];
            const float4* w4 = (const float4*)&wlds[c * 16];
            float4 wv[4];
#pragma unroll
            for (int j = 0; j < 4; j++) wv[j] = w4[j];
            const float* wf = (const float*)wv;
#pragma unroll
            for (int o = 0; o < 8; o++) {
                th0[o] = fmaf(wf[o], xv.x, th0[o]);
                th1[o] = fmaf(wf[o], xv.y, th1[o]);
                ph0[o] = fmaf(wf[8 + o], xv.x, ph0[o]);
                ph1[o] = fmaf(wf[8 + o], xv.y, ph1[o]);
            }
        }
        // theta store: pixels 2*p2, 2*p2+1 -> 64 contiguous bytes
        float4* tw = (float4*)(theta + ((size_t)b * NN + 2 * p2) * 8);
        tw[0] = make_float4(th0[0], th0[1], th0[2], th0[3]);
        tw[1] = make_float4(th0[4], th0[5], th0[6], th0[7]);
        tw[2] = make_float4(th1[0], th1[1], th1[2], th1[3]);
        tw[3] = make_float4(th1[4], th1[5], th1[6], th1[7]);
        // phi maxpool + store
        float phm[8];
#pragma unroll
        for (int i = 0; i < 8; i++) phm[i] = fmaxf(ph0[i], ph1[i]);
#pragma unroll
        for (int i = 0; i < 8; i++) phm[i] = fmaxf(phm[i], __shfl_xor(phm[i], 32));
        if (l < 32) {
            float4* pw = (float4*)(phi + ((size_t)b * MM + m) * 8);
            pw[0] = make_float4(phm[0], phm[1], phm[2], phm[3]);
            pw[1] = make_float4(phm[4], phm[5], phm[6], phm[7]);
        }
    } else {
        float gg0[32], gg1[32];
#pragma unroll
        for (int i = 0; i < 32; i++) { gg0[i] = gg1[i] = 0.f; }
#pragma unroll 4
        for (int c = 0; c < 64; c++) {
            float2 xv = x2[c * (NN / 2) + p2];
            const float4* w4 = (const float4*)&wlds[c * 32];
            float4 wv[8];
#pragma unroll
            for (int j = 0; j < 8; j++) wv[j] = w4[j];
            const float* wf = (const float*)wv;
#pragma unroll
            for (int o = 0; o < 32; o++) {
                gg0[o] = fmaf(wf[o], xv.x, gg0[o]);
                gg1[o] = fmaf(wf[o], xv.y, gg1[o]);
            }
        }
        float ggm[32];
#pragma unroll
        for (int i = 0; i < 32; i++) ggm[i] = fmaxf(gg0[i], gg1[i]);
#pragma unroll
        for (int i = 0; i < 32; i++) ggm[i] = fmaxf(ggm[i], __shfl_xor(ggm[i], 32));
        if (l < 32) {
            unsigned up[16];
#pragma unroll
            for (int k = 0; k < 16; k++) up[k] = pack_bf16(ggm[2*k], ggm[2*k+1]);
            uint4* gw = (uint4*)(gpk + ((size_t)b * MM + m) * 16);
#pragma unroll
            for (int j = 0; j < 4; j++)
                gw[j] = make_uint4(up[4*j], up[4*j+1], up[4*j+2], up[4*j+3]);
        }
    }
}

// ---------------------------------------------------------------------------
// Kernel 2: flash-style attention over an M-chunk, 4 pixels/thread.
// __launch_bounds__(256,2): ~180 regs of live state (acc 128 + theta 32)
// MUST stay in the register file -- (256,4) caps at 128 and spills acc to
// scratch (R4: 7 GB HBM scratch traffic, 1.4 ms). Do not raise occupancy.
// 64-row LDS tiles: phi fp32 (2 KB) + g bf16-packed (4 KB).
// Scores computed on pixel-pairs via packed v2f FMA (16 instrs/m-row),
// accumulate via v_pk_fma_f32 (64 instrs/m-row).
// No max pass: scores ~N(0,2.8^2); fp32 exp overflows only past s=88.
// ---------------------------------------------------------------------------
__global__ __launch_bounds__(256, 2) void attn_kernel(
    const float* __restrict__ theta,    // [B][N][8]
    const float* __restrict__ phi,      // [B][M][8]
    const unsigned* __restrict__ gpk,   // [B][M][16]
    unsigned* __restrict__ pacc,        // [B][nchunk][17][N] (16 pk + den)
    int nchunk)
{
    __shared__ float4 ph4[128];     // 64 m-rows x 8 fp32
    __shared__ uint4  gl4[256];     // 64 m-rows x 16 packed bf16-pairs

    const int b     = blockIdx.z;
    const int chunk = blockIdx.y;
    const int blk   = blockIdx.x;
    const int t     = threadIdx.x;
    const int nb    = blk * 1024 + t;     // pixel 0 of this thread's 4
    const int mc    = MM / nchunk;
    const int mbase = chunk * mc;

    // theta for 4 pixels, interleaved into pixel-pairs for packed score FMA
    v2f t01[8], t23[8];
    {
        float th[4][8];
#pragma unroll
        for (int p = 0; p < 4; p++) {
            const float4* tp =
                (const float4*)(theta + ((size_t)b * NN + nb + p * 256) * 8);
            float4 a = tp[0], bq = tp[1];
            th[p][0]=a.x; th[p][1]=a.y; th[p][2]=a.z; th[p][3]=a.w;
            th[p][4]=bq.x; th[p][5]=bq.y; th[p][6]=bq.z; th[p][7]=bq.w;
        }
#pragma unroll
        for (int i = 0; i < 8; i++) {
            t01[i].x = th[0][i]; t01[i].y = th[1][i];
            t23[i].x = th[2][i]; t23[i].y = th[3][i];
        }
    }

    v2f acc[4][16];
#pragma unroll
    for (int p = 0; p < 4; p++)
#pragma unroll
        for (int k = 0; k < 16; k++) acc[p][k] = (v2f)(0.f);
    v2f den01 = (v2f)(0.f), den23 = (v2f)(0.f);

    for (int mt = 0; mt < mc; mt += 64) {
        const int base = mbase + mt;
        if (t < 128)
            ph4[t] = ((const float4*)(phi + ((size_t)b * MM + base) * 8))[t];
        gl4[t] = ((const uint4*)(gpk + ((size_t)b * MM + base) * 16))[t];
        __syncthreads();

#pragma unroll 2
        for (int mm = 0; mm < 64; mm++) {
            float4 p0 = ph4[2 * mm], p1 = ph4[2 * mm + 1];
            v2f s01 = t01[0] * (v2f)(p0.x);
            v2f s23 = t23[0] * (v2f)(p0.x);
            s01 = __builtin_elementwise_fma(t01[1], (v2f)(p0.y), s01);
            s23 = __builtin_elementwise_fma(t23[1], (v2f)(p0.y), s23);
            s01 = __builtin_elementwise_fma(t01[2], (v2f)(p0.z), s01);
            s23 = __builtin_elementwise_fma(t23[2], (v2f)(p0.z), s23);
            s01 = __builtin_elementwise_fma(t01[3], (v2f)(p0.w), s01);
            s23 = __builtin_elementwise_fma(t23[3], (v2f)(p0.w), s23);
            s01 = __builtin_elementwise_fma(t01[4], (v2f)(p1.x), s01);
            s23 = __builtin_elementwise_fma(t23[4], (v2f)(p1.x), s23);
            s01 = __builtin_elementwise_fma(t01[5], (v2f)(p1.y), s01);
            s23 = __builtin_elementwise_fma(t23[5], (v2f)(p1.y), s23);
            s01 = __builtin_elementwise_fma(t01[6], (v2f)(p1.z), s01);
            s23 = __builtin_elementwise_fma(t23[6], (v2f)(p1.z), s23);
            s01 = __builtin_elementwise_fma(t01[7], (v2f)(p1.w), s01);
            s23 = __builtin_elementwise_fma(t23[7], (v2f)(p1.w), s23);

            float e0 = __expf(s01.x), e1 = __expf(s01.y);
            float e2v = __expf(s23.x), e3 = __expf(s23.y);
            den01.x += e0; den01.y += e1; den23.x += e2v; den23.y += e3;
            v2f eb[4];
            eb[0] = (v2f)(e0); eb[1] = (v2f)(e1);
            eb[2] = (v2f)(e2v); eb[3] = (v2f)(e3);

#pragma unroll
            for (int j2 = 0; j2 < 4; j2++) {
                uint4 gq = gl4[mm * 4 + j2];
                unsigned uu[4] = {gq.x, gq.y, gq.z, gq.w};
#pragma unroll
                for (int w = 0; w < 4; w++) {
                    v2f gp = unpack_bf16(uu[w]);
                    int k = j2 * 4 + w;
                    acc[0][k] = __builtin_elementwise_fma(gp, eb[0], acc[0][k]);
                    acc[1][k] = __builtin_elementwise_fma(gp, eb[1], acc[1][k]);
                    acc[2][k] = __builtin_elementwise_fma(gp, eb[2], acc[2][k]);
                    acc[3][k] = __builtin_elementwise_fma(gp, eb[3], acc[3][k]);
                }
            }
        }
        __syncthreads();
    }

    unsigned* pb = pacc + (size_t)(b * nchunk + chunk) * 17 * NN;
    const float dens[4] = {den01.x, den01.y, den23.x, den23.y};
#pragma unroll
    for (int p = 0; p < 4; p++) {
        const int n = nb + p * 256;
#pragma unroll
        for (int k = 0; k < 16; k++)
            pb[(size_t)k * NN + n] = pack_bf16(acc[p][k].x, acc[p][k].y);
        pb[(size_t)16 * NN + n] = __float_as_uint(dens[p]);
    }
}

// ---------------------------------------------------------------------------
// Kernel 3: combine chunk partials (packed bf16 pairs), normalize, w_o
// projection via wave-uniform scalar loads + pk-fma, gamma + residual.
// 1 px/thread, 256 blocks x 4 waves.
// ---------------------------------------------------------------------------
__global__ __launch_bounds__(256, 4) void reduce_kernel(
    const unsigned* __restrict__ pacc,  // [B][nchunk][17][N]
    const float* __restrict__ w_o,      // [64][32]
    const float* __restrict__ gamma_p,
    const float* __restrict__ x,        // [B][C][N]
    float* __restrict__ out,            // [B][C][N]
    int nchunk)
{
    const int b = blockIdx.y;
    const int t = threadIdx.x;
    const int n = blockIdx.x * 256 + t;

    v2f ov[16];
#pragma unroll
    for (int k = 0; k < 16; k++) ov[k] = (v2f)(0.f);
    float den = 0.f;

    for (int ch = 0; ch < nchunk; ch++) {
        const unsigned* pb = pacc + (size_t)(b * nchunk + ch) * 17 * NN + n;
#pragma unroll
        for (int k = 0; k < 16; k++) ov[k] += unpack_bf16(pb[(size_t)k * NN]);
        den += __uint_as_float(pb[(size_t)16 * NN]);
    }
    const float inv = 1.f / den;
#pragma unroll
    for (int k = 0; k < 16; k++) ov[k] *= (v2f)(inv);

    const float gamma = gamma_p[0];
#pragma unroll 4
    for (int co = 0; co < 64; co++) {
        const v2f* wrow = (const v2f*)(w_o + co * 32);   // uniform -> s_load
        v2f s2 = (v2f)(0.f);
#pragma unroll
        for (int k = 0; k < 16; k++)
            s2 = __builtin_elementwise_fma(wrow[k], ov[k], s2);
        float v = s2.x + s2.y;
        size_t oi = ((size_t)b * CC + co) * NN + n;
        out[oi] = fmaf(gamma, v, x[oi]);
    }
}

extern "C" void kernel_launch(void* const* d_in, const int* in_sizes, int n_in,
                              void* d_out, int out_size, void* d_ws, size_t ws_size,
                              hipStream_t stream) {
    const float* x       = (const float*)d_in[0];
    const float* w_theta = (const float*)d_in[1];
    const float* w_phi   = (const float*)d_in[2];
    const float* w_g     = (const float*)d_in[3];
    const float* w_o     = (const float*)d_in[4];
    const float* gamma   = (const float*)d_in[5];
    float* out = (float*)d_out;

    // workspace: theta [B][N][8] f32, phi [B][M][8] f32,
    //            gpk [B][M][16] u32, pacc [B][nchunk][17][N] u32
    float*    theta_ws = (float*)d_ws;
    float*    phi_ws   = theta_ws + (size_t)BB * NN * 8;    // 524288 f
    unsigned* gpk_ws   = (unsigned*)(phi_ws + (size_t)BB * MM * 8);  // 131072 f
    unsigned* pacc     = gpk_ws + (size_t)BB * MM * 16;     // 262144 u
    const size_t base_w = (size_t)BB * NN * 8 + (size_t)BB * MM * 8
                        + (size_t)BB * MM * 16;             // 4-byte words

    int nchunk = 8;   // M-split: 512 attn blocks = 2/CU at (256,2)
    while (nchunk > 1 &&
           (base_w + (size_t)BB * nchunk * 17 * NN) * 4 > ws_size)
        nchunk >>= 1;

    proj_kernel<<<dim3(16, BB, 2), 128, 0, stream>>>(
        x, w_theta, w_phi, w_g, theta_ws, phi_ws, gpk_ws);

    attn_kernel<<<dim3(NN / 1024, nchunk, BB), 256, 0, stream>>>(
        theta_ws, phi_ws, gpk_ws, pacc, nchunk);

    reduce_kernel<<<dim3(NN / 256, BB), 256, 0, stream>>>(
        pacc, w_o, gamma, x, out, nchunk);
}

// Round 9
// 123.501 us; speedup vs baseline: 12.0694x; 1.6279x over previous
//
#include <hip/hip_runtime.h>

typedef _Float16 half4v __attribute__((ext_vector_type(4)));
typedef float    float4v __attribute__((ext_vector_type(4)));

#define BB 16
#define CC 64
#define NN 4096   // H*W
#define MM 1024   // H*W/4
#define LN256 5.545177444479562f

static __device__ __forceinline__ float4v mfma16(half4v a, half4v b, float4v c) {
    return __builtin_amdgcn_mfma_f32_16x16x16f16(a, b, c, 0, 0, 0);
}

// fp32 pair -> packed fp16 pair (as u32), for stored projections / weights
__device__ __forceinline__ unsigned pk2(float a, float b) {
    union { _Float16 h[2]; unsigned u; } cv;
    cv.h[0] = (_Float16)a; cv.h[1] = (_Float16)b;
    return cv.u;
}

// ---------------------------------------------------------------------------
// Kernel 1: projections + fused 2x2 maxpool, fp16 outputs.
//   z=0: theta [B][N][8] + phi [B][M][8];  z=1: gT [B][32][M] (transposed!)
// 128 threads, 2 px/thread; vertical pool partner = lane^32.
// ---------------------------------------------------------------------------
__global__ __launch_bounds__(128, 4) void proj_kernel(
    const float* __restrict__ x,      // [B][C][N]
    const float* __restrict__ w_th,   // [8][64]
    const float* __restrict__ w_ph,   // [8][64]
    const float* __restrict__ w_g,    // [32][64]
    _Float16* __restrict__ theta,     // [B][N][8]
    _Float16* __restrict__ phi,       // [B][M][8]
    _Float16* __restrict__ gT)        // [B][32][M]
{
    __shared__ float wlds[64 * 32];

    const int b   = blockIdx.y;
    const int blk = blockIdx.x;
    const int z   = blockIdx.z;
    const int t   = threadIdx.x;

    if (z == 0) {
        for (int i = t; i < 1024; i += 128) {       // [c][o]: o<8 th, o<16 ph
            int c = i >> 4, o = i & 15;
            wlds[i] = (o < 8) ? w_th[o * 64 + c] : w_ph[(o - 8) * 64 + c];
        }
    } else {
        for (int i = t; i < 2048; i += 128) {       // [c][o]
            int c = i >> 5, o = i & 31;
            wlds[i] = w_g[o * 64 + c];
        }
    }
    __syncthreads();

    const float2* x2 = (const float2*)(x + (size_t)b * CC * NN);
    const int p2 = blk * 128 + t;
    const int l = t & 63, w = t >> 6;
    const int m = (blk * 2 + w) * 32 + (l & 31);

    if (z == 0) {
        float th0[8], th1[8], ph0[8], ph1[8];
#pragma unroll
        for (int i = 0; i < 8; i++) { th0[i]=th1[i]=ph0[i]=ph1[i]=0.f; }
#pragma unroll 4
        for (int c = 0; c < 64; c++) {
            float2 xv = x2[c * (NN / 2) + p2];
            const float4* w4 = (const float4*)&wlds[c * 16];
            float4 wv[4];
#pragma unroll
            for (int j = 0; j < 4; j++) wv[j] = w4[j];
            const float* wf = (const float*)wv;
#pragma unroll
            for (int o = 0; o < 8; o++) {
                th0[o] = fmaf(wf[o], xv.x, th0[o]);
                th1[o] = fmaf(wf[o], xv.y, th1[o]);
                ph0[o] = fmaf(wf[8 + o], xv.x, ph0[o]);
                ph1[o] = fmaf(wf[8 + o], xv.y, ph1[o]);
            }
        }
        uint4* tw = (uint4*)(theta + ((size_t)b * NN + 2 * p2) * 8);
        tw[0] = make_uint4(pk2(th0[0],th0[1]), pk2(th0[2],th0[3]),
                           pk2(th0[4],th0[5]), pk2(th0[6],th0[7]));
        tw[1] = make_uint4(pk2(th1[0],th1[1]), pk2(th1[2],th1[3]),
                           pk2(th1[4],th1[5]), pk2(th1[6],th1[7]));
        float phm[8];
#pragma unroll
        for (int i = 0; i < 8; i++) phm[i] = fmaxf(ph0[i], ph1[i]);
#pragma unroll
        for (int i = 0; i < 8; i++) phm[i] = fmaxf(phm[i], __shfl_xor(phm[i], 32));
        if (l < 32) {
            uint4* pw = (uint4*)(phi + ((size_t)b * MM + m) * 8);
            pw[0] = make_uint4(pk2(phm[0],phm[1]), pk2(phm[2],phm[3]),
                               pk2(phm[4],phm[5]), pk2(phm[6],phm[7]));
        }
    } else {
        float gg0[32], gg1[32];
#pragma unroll
        for (int i = 0; i < 32; i++) { gg0[i] = gg1[i] = 0.f; }
#pragma unroll 4
        for (int c = 0; c < 64; c++) {
            float2 xv = x2[c * (NN / 2) + p2];
            const float4* w4 = (const float4*)&wlds[c * 32];
            float4 wv[8];
#pragma unroll
            for (int j = 0; j < 8; j++) wv[j] = w4[j];
            const float* wf = (const float*)wv;
#pragma unroll
            for (int o = 0; o < 32; o++) {
                gg0[o] = fmaf(wf[o], xv.x, gg0[o]);
                gg1[o] = fmaf(wf[o], xv.y, gg1[o]);
            }
        }
        float ggm[32];
#pragma unroll
        for (int i = 0; i < 32; i++) ggm[i] = fmaxf(gg0[i], gg1[i]);
#pragma unroll
        for (int i = 0; i < 32; i++) ggm[i] = fmaxf(ggm[i], __shfl_xor(ggm[i], 32));
        // lanes 0-31 write channels 0-15, lanes 32-63 write channels 16-31
        const int cofs = (l < 32) ? 0 : 16;
        _Float16* gp = gT + ((size_t)b * 32 + cofs) * MM + m;
#pragma unroll
        for (int c2 = 0; c2 < 16; c2++)
            gp[(size_t)c2 * MM] = (_Float16)ggm[cofs + c2];
    }
}

// ---------------------------------------------------------------------------
// Kernel 2: fully-fused MFMA attention, TWO-PASS exact softmax.
// Pass 1: S^T = phi.theta^T only, tracking per-column (per-n) max; quads
// sharing a column reduce via shfl_xor(16|32). Pass 2: P = exp(s-mx+ln256)
// (P_max = 256 exactly: no fp16 overflow; den >= 256: no zero-denominator
// even if the matrix pipe flushes subnormal fp16 inputs -- the R8 NaN).
// C-layout of P^T == B-operand layout, so O^T = gT.P^T chains in-register;
// ones-row A-frag gives the denominator; third MFMA applies w_o + residual.
// ---------------------------------------------------------------------------
__global__ __launch_bounds__(256, 4) void attn_kernel(
    const _Float16* __restrict__ theta,  // [B][N][8]
    const _Float16* __restrict__ phi,    // [B][M][8]
    const _Float16* __restrict__ gT,     // [B][32][M]
    const float* __restrict__ w_o,       // [64][32]
    const float* __restrict__ gamma_p,
    const float* __restrict__ x,         // [B][C][N]
    float* __restrict__ out)             // [B][C][N]
{
    // phi rows padded to 24 f16 (48 B): elems 8..15 are the K-pad zeros.
    __shared__ __align__(16) _Float16 phl[128 * 24];   // 6 KB
    __shared__ __align__(16) _Float16 gl[32 * 136];    // 8.5 KB (stride 136)

    const int b    = blockIdx.y;
    const int t    = threadIdx.x;
    const int wave = t >> 6;
    const int lane = t & 63;
    const int col  = lane & 15;       // n-col / c-row / co-row of frags
    const int q    = lane >> 4;       // quad
    const int nbase = blockIdx.x * 64 + wave * 16;

    const float4v zero4 = {0.f, 0.f, 0.f, 0.f};

    // zero the phi K-pad once (elements 8..15 of each row)
    if (t < 128)
        *(float4*)&phl[t * 24 + 8] = make_float4(0.f, 0.f, 0.f, 0.f);

    // theta B-frag for this wave's 16 n (k = q*4+j; k>=8 is zero pad)
    half4v thB = (half4v){0, 0, 0, 0};
    if (q < 2)
        thB = *(const half4v*)(theta + ((size_t)b * NN + nbase + col) * 8 + q * 4);

    // ones A-frag: output row 0 = softmax denominator
    half4v onesA = (half4v){0, 0, 0, 0};
    if (col == 0) {
        onesA[0] = (_Float16)1; onesA[1] = (_Float16)1;
        onesA[2] = (_Float16)1; onesA[3] = (_Float16)1;
    }

    // ---- pass 1: exact per-column score max ----
    float mx = -1e30f;
    for (int m0 = 0; m0 < MM; m0 += 128) {
        __syncthreads();
        if (t < 128)
            *(float4*)&phl[t * 24] =
                *(const float4*)(phi + ((size_t)b * MM + m0 + t) * 8);
        __syncthreads();
#pragma unroll
        for (int mt = 0; mt < 8; mt++) {
            half4v af = *(const half4v*)&phl[(mt * 16 + col) * 24 + q * 4];
            float4v S = mfma16(af, thB, zero4);
            mx = fmaxf(mx, fmaxf(fmaxf(S.x, S.y), fmaxf(S.z, S.w)));
        }
    }
    // reduce across the 4 quads that hold the same column (lane bits 4,5)
    mx = fmaxf(mx, __shfl_xor(mx, 16));
    mx = fmaxf(mx, __shfl_xor(mx, 32));
    const float shift = mx - LN256;   // P = e^(s-mx) * 256 <= 256

    // ---- pass 2: P, O^T, denominator ----
    float4v acc0 = zero4, acc1 = zero4, accd = zero4;

    for (int m0 = 0; m0 < MM; m0 += 128) {
        __syncthreads();
        if (t < 128)
            *(float4*)&phl[t * 24] =
                *(const float4*)(phi + ((size_t)b * MM + m0 + t) * 8);
        {
            int c = t >> 3, seg = (t & 7) * 16;
            const _Float16* src = gT + ((size_t)b * 32 + c) * MM + m0 + seg;
            float4 v0 = *(const float4*)src;
            float4 v1 = *(const float4*)(src + 8);
            *(float4*)&gl[c * 136 + seg]     = v0;
            *(float4*)&gl[c * 136 + seg + 8] = v1;
        }
        __syncthreads();

#pragma unroll 2
        for (int mt = 0; mt < 8; mt++) {
            // A-frag of phi: row = m-local = col, k = q*4+j (pad -> zeros)
            half4v af = *(const half4v*)&phl[(mt * 16 + col) * 24 + q * 4];
            float4v S = mfma16(af, thB, zero4);
            // S^T[m = mt*16 + q*4 + r][n = nbase + col]
            half4v P;
            P[0] = (_Float16)__expf(S.x - shift);
            P[1] = (_Float16)__expf(S.y - shift);
            P[2] = (_Float16)__expf(S.z - shift);
            P[3] = (_Float16)__expf(S.w - shift);
            // A-frags of gT: row = c-local = col, k = m-local = q*4+j
            half4v ag0 = *(const half4v*)&gl[col * 136 + mt * 16 + q * 4];
            half4v ag1 = *(const half4v*)&gl[(col + 16) * 136 + mt * 16 + q * 4];
            acc0 = mfma16(ag0, P, acc0);   // O^T c 0-15
            acc1 = mfma16(ag1, P, acc1);   // O^T c 16-31
            accd = mfma16(onesA, P, accd); // row 0 = denominator
        }
    }

    // denominator: accd row 0 lives on lanes 0-15 (q==0), element .x
    float dv = __shfl(accd.x, col);            // den[n] broadcast to all quads
    float sc = gamma_p[0] / dv;                // fold gamma into the scale

    // normalized O^T as B-frags for the w_o MFMA
    half4v B0, B1;
    B0[0] = (_Float16)(acc0.x * sc); B0[1] = (_Float16)(acc0.y * sc);
    B0[2] = (_Float16)(acc0.z * sc); B0[3] = (_Float16)(acc0.w * sc);
    B1[0] = (_Float16)(acc1.x * sc); B1[1] = (_Float16)(acc1.y * sc);
    B1[2] = (_Float16)(acc1.z * sc); B1[3] = (_Float16)(acc1.w * sc);

#pragma unroll
    for (int ct = 0; ct < 4; ct++) {
        // w_o A-frags: row = co-local = col, k = c = half*16 + q*4+j
        const float* wp = w_o + (size_t)(ct * 16 + col) * 32 + q * 4;
        float4 w0 = *(const float4*)wp;           // c 0-15 part
        float4 w1 = *(const float4*)(wp + 16);    // c 16-31 part
        half4v wa, wb;
        wa[0] = (_Float16)w0.x; wa[1] = (_Float16)w0.y;
        wa[2] = (_Float16)w0.z; wa[3] = (_Float16)w0.w;
        wb[0] = (_Float16)w1.x; wb[1] = (_Float16)w1.y;
        wb[2] = (_Float16)w1.z; wb[3] = (_Float16)w1.w;
        float4v D = mfma16(wa, B0, zero4);
        D = mfma16(wb, B1, D);
        // D[co-local = q*4+r][n = col]; out = D + x (gamma already in sc)
#pragma unroll
        for (int r = 0; r < 4; r++) {
            int co = ct * 16 + q * 4 + r;
            size_t idx = ((size_t)b * CC + co) * NN + nbase + col;
            out[idx] = D[r] + x[idx];
        }
    }
}

extern "C" void kernel_launch(void* const* d_in, const int* in_sizes, int n_in,
                              void* d_out, int out_size, void* d_ws, size_t ws_size,
                              hipStream_t stream) {
    const float* x       = (const float*)d_in[0];
    const float* w_theta = (const float*)d_in[1];
    const float* w_phi   = (const float*)d_in[2];
    const float* w_g     = (const float*)d_in[3];
    const float* w_o     = (const float*)d_in[4];
    const float* gamma   = (const float*)d_in[5];
    float* out = (float*)d_out;

    // fp16 workspace: theta [B][N][8], phi [B][M][8], gT [B][32][M] = 2.4 MB
    _Float16* theta_ws = (_Float16*)d_ws;
    _Float16* phi_ws   = theta_ws + (size_t)BB * NN * 8;
    _Float16* gT_ws    = phi_ws   + (size_t)BB * MM * 8;

    proj_kernel<<<dim3(16, BB, 2), 128, 0, stream>>>(
        x, w_theta, w_phi, w_g, theta_ws, phi_ws, gT_ws);

    attn_kernel<<<dim3(NN / 64, BB), 256, 0, stream>>>(
        theta_ws, phi_ws, gT_ws, w_o, gamma, x, out);
}

// Round 10
// 118.653 us; speedup vs baseline: 12.5625x; 1.0409x over previous
//
#include <hip/hip_runtime.h>

typedef _Float16 half4v __attribute__((ext_vector_type(4)));
typedef _Float16 h2     __attribute__((ext_vector_type(2)));
typedef float    float4v __attribute__((ext_vector_type(4)));

#define BB 16
#define CC 64
#define NN 4096   // H*W
#define MM 1024   // H*W/4
#define LN256 5.545177444479562f

static __device__ __forceinline__ float4v mfma16(half4v a, half4v b, float4v c) {
    return __builtin_amdgcn_mfma_f32_16x16x16f16(a, b, c, 0, 0, 0);
}

// fp32 pair -> packed fp16 pair (as u32)
__device__ __forceinline__ unsigned pk2(float a, float b) {
    union { _Float16 h[2]; unsigned u; } cv;
    cv.h[0] = (_Float16)a; cv.h[1] = (_Float16)b;
    return cv.u;
}
__device__ __forceinline__ h2 ash2(unsigned u) {
    union { unsigned u; h2 h; } c; c.u = u; return c.h;
}
__device__ __forceinline__ h2 hmax2(h2 a, h2 b) {
    h2 r;
    r.x = (a.x > b.x) ? a.x : b.x;
    r.y = (a.y > b.y) ? a.y : b.y;
    return r;
}
__device__ __forceinline__ h2 shfl_xor_h2(h2 v, int m) {
    union { h2 h; int i; } c; c.h = v; c.i = __shfl_xor(c.i, m);
    return c.h;
}

// ---------------------------------------------------------------------------
// Kernel 1: projections + fused 2x2 maxpool, fp16 outputs.
//   z=0: theta [B][N][8] + phi [B][M][8] (fp32 accum, proven path)
//   z=1: gT [B][32][M] via packed fp16 weights + v_pk_fma_f16
//        (g is fp16-quantized at store anyway; halves LDS reads and VALU)
// 128 threads, 2 px/thread; vertical pool partner = lane^32.
// ---------------------------------------------------------------------------
__global__ __launch_bounds__(128, 4) void proj_kernel(
    const float* __restrict__ x,      // [B][C][N]
    const float* __restrict__ w_th,   // [8][64]
    const float* __restrict__ w_ph,   // [8][64]
    const float* __restrict__ w_g,    // [32][64]
    _Float16* __restrict__ theta,     // [B][N][8]
    _Float16* __restrict__ phi,       // [B][M][8]
    _Float16* __restrict__ gT)        // [B][32][M]
{
    __shared__ __align__(16) float wlds[64 * 16];   // 4 KB (z1 reuses as u32)
    unsigned* wl2 = (unsigned*)wlds;

    const int b   = blockIdx.y;
    const int blk = blockIdx.x;
    const int z   = blockIdx.z;
    const int t   = threadIdx.x;

    if (z == 0) {
        for (int i = t; i < 1024; i += 128) {       // [c][o]: o<8 th, o<16 ph
            int c = i >> 4, o = i & 15;
            wlds[i] = (o < 8) ? w_th[o * 64 + c] : w_ph[(o - 8) * 64 + c];
        }
    } else {
        for (int i = t; i < 1024; i += 128) {       // [c][o2] h2 channel-pairs
            int c = i >> 4, o2 = i & 15;
            wl2[i] = pk2(w_g[(2 * o2) * 64 + c], w_g[(2 * o2 + 1) * 64 + c]);
        }
    }
    __syncthreads();

    const float2* x2 = (const float2*)(x + (size_t)b * CC * NN);
    const int p2 = blk * 128 + t;
    const int l = t & 63, w = t >> 6;
    const int m = (blk * 2 + w) * 32 + (l & 31);

    if (z == 0) {
        float th0[8], th1[8], ph0[8], ph1[8];
#pragma unroll
        for (int i = 0; i < 8; i++) { th0[i]=th1[i]=ph0[i]=ph1[i]=0.f; }
#pragma unroll 4
        for (int c = 0; c < 64; c++) {
            float2 xv = x2[c * (NN / 2) + p2];
            const float4* w4 = (const float4*)&wlds[c * 16];
            float4 wv[4];
#pragma unroll
            for (int j = 0; j < 4; j++) wv[j] = w4[j];
            const float* wf = (const float*)wv;
#pragma unroll
            for (int o = 0; o < 8; o++) {
                th0[o] = fmaf(wf[o], xv.x, th0[o]);
                th1[o] = fmaf(wf[o], xv.y, th1[o]);
                ph0[o] = fmaf(wf[8 + o], xv.x, ph0[o]);
                ph1[o] = fmaf(wf[8 + o], xv.y, ph1[o]);
            }
        }
        uint4* tw = (uint4*)(theta + ((size_t)b * NN + 2 * p2) * 8);
        tw[0] = make_uint4(pk2(th0[0],th0[1]), pk2(th0[2],th0[3]),
                           pk2(th0[4],th0[5]), pk2(th0[6],th0[7]));
        tw[1] = make_uint4(pk2(th1[0],th1[1]), pk2(th1[2],th1[3]),
                           pk2(th1[4],th1[5]), pk2(th1[6],th1[7]));
        float phm[8];
#pragma unroll
        for (int i = 0; i < 8; i++) phm[i] = fmaxf(ph0[i], ph1[i]);
#pragma unroll
        for (int i = 0; i < 8; i++) phm[i] = fmaxf(phm[i], __shfl_xor(phm[i], 32));
        if (l < 32) {
            uint4* pw = (uint4*)(phi + ((size_t)b * MM + m) * 8);
            pw[0] = make_uint4(pk2(phm[0],phm[1]), pk2(phm[2],phm[3]),
                               pk2(phm[4],phm[5]), pk2(phm[6],phm[7]));
        }
    } else {
        h2 ga[16], gb[16];
#pragma unroll
        for (int i = 0; i < 16; i++) { ga[i] = (h2)0; gb[i] = (h2)0; }
#pragma unroll 4
        for (int c = 0; c < 64; c++) {
            float2 xv = x2[c * (NN / 2) + p2];
            const uint4* w4 = (const uint4*)&wl2[c * 16];
            uint4 q0 = w4[0], q1 = w4[1], q2 = w4[2], q3 = w4[3];
            unsigned wv[16] = {q0.x,q0.y,q0.z,q0.w, q1.x,q1.y,q1.z,q1.w,
                               q2.x,q2.y,q2.z,q2.w, q3.x,q3.y,q3.z,q3.w};
            _Float16 hx = (_Float16)xv.x, hy = (_Float16)xv.y;
            h2 xa; xa.x = hx; xa.y = hx;
            h2 xb; xb.x = hy; xb.y = hy;
#pragma unroll
            for (int k = 0; k < 16; k++) {
                ga[k] = __builtin_elementwise_fma(ash2(wv[k]), xa, ga[k]);
                gb[k] = __builtin_elementwise_fma(ash2(wv[k]), xb, gb[k]);
            }
        }
        h2 gm[16];
#pragma unroll
        for (int k = 0; k < 16; k++) gm[k] = hmax2(ga[k], gb[k]);
#pragma unroll
        for (int k = 0; k < 16; k++) gm[k] = hmax2(gm[k], shfl_xor_h2(gm[k], 32));
        // lanes 0-31 write channels 0-15, lanes 32-63 write channels 16-31
        const int k0 = (l < 32) ? 0 : 8;
        _Float16* gp = gT + ((size_t)b * 32 + 2 * k0) * MM + m;
#pragma unroll
        for (int k = 0; k < 8; k++) {
            h2 v = gm[k0 + k];
            gp[(size_t)(2 * k) * MM]     = v.x;
            gp[(size_t)(2 * k + 1) * MM] = v.y;
        }
    }
}

// ---------------------------------------------------------------------------
// Kernel 2: fully-fused MFMA attention, TWO-PASS exact softmax.
// All of phi[b] (16 KB, unpadded) persists in LDS -> pass 1 (max) is a
// barrier-free 64-MFMA loop; A-frag k-pad handled by predicating q<2 reads
// to zero. Pass 2: P = exp(s-mx+ln256) (P_max = 256: no fp16 overflow, no
// subnormal-flush zero-denominator). C-layout of P^T == B-operand layout ->
// O^T = gT.P^T chains in-register; ones-row A-frag gives the denominator;
// third MFMA applies w_o; epilogue adds x. LDS 24.5 KB -> 4 blocks/CU.
// ---------------------------------------------------------------------------
__global__ __launch_bounds__(256, 4) void attn_kernel(
    const _Float16* __restrict__ theta,  // [B][N][8]
    const _Float16* __restrict__ phi,    // [B][M][8]
    const _Float16* __restrict__ gT,     // [B][32][M]
    const float* __restrict__ w_o,       // [64][32]
    const float* __restrict__ gamma_p,
    const float* __restrict__ x,         // [B][C][N]
    float* __restrict__ out)             // [B][C][N]
{
    __shared__ __align__(16) _Float16 phl[MM * 8];     // 16 KB, all of phi[b]
    __shared__ __align__(16) _Float16 gl[32 * 136];    // 8.5 KB (stride 136)

    const int b    = blockIdx.y;
    const int t    = threadIdx.x;
    const int wave = t >> 6;
    const int lane = t & 63;
    const int col  = lane & 15;       // n-col / c-row / co-row of frags
    const int q    = lane >> 4;       // quad
    const int nbase = blockIdx.x * 64 + wave * 16;

    const float4v zero4 = {0.f, 0.f, 0.f, 0.f};
    const half4v zeroh = {0, 0, 0, 0};

    // stage ALL of phi[b]: 1024 float4s
    {
        const float4* src = (const float4*)(phi + (size_t)b * MM * 8);
        float4* dst = (float4*)phl;
#pragma unroll
        for (int i = 0; i < 4; i++) dst[t + i * 256] = src[t + i * 256];
    }

    // theta B-frag for this wave's 16 n (k = q*4+j; k>=8 is zero pad)
    half4v thB = zeroh;
    if (q < 2)
        thB = *(const half4v*)(theta + ((size_t)b * NN + nbase + col) * 8 + q * 4);

    // ones A-frag: output row 0 = softmax denominator
    half4v onesA = zeroh;
    if (col == 0) {
        onesA[0] = (_Float16)1; onesA[1] = (_Float16)1;
        onesA[2] = (_Float16)1; onesA[3] = (_Float16)1;
    }

    __syncthreads();

    // ---- pass 1: exact per-column score max (barrier-free) ----
    float mx = -1e30f;
#pragma unroll 4
    for (int mt = 0; mt < 64; mt++) {
        half4v af = zeroh;
        if (q < 2)
            af = *(const half4v*)&phl[(mt * 16 + col) * 8 + q * 4];
        float4v S = mfma16(af, thB, zero4);
        mx = fmaxf(mx, fmaxf(fmaxf(S.x, S.y), fmaxf(S.z, S.w)));
    }
    // reduce across the 4 quads that hold the same column (lane bits 4,5)
    mx = fmaxf(mx, __shfl_xor(mx, 16));
    mx = fmaxf(mx, __shfl_xor(mx, 32));
    const float shift = mx - LN256;   // P = e^(s-mx) * 256 <= 256

    // ---- pass 2: P, O^T, denominator ----
    float4v acc0 = zero4, acc1 = zero4, accd = zero4;

    for (int m0 = 0; m0 < MM; m0 += 128) {
        __syncthreads();
        {
            int c = t >> 3, seg = (t & 7) * 16;
            const _Float16* src = gT + ((size_t)b * 32 + c) * MM + m0 + seg;
            float4 v0 = *(const float4*)src;
            float4 v1 = *(const float4*)(src + 8);
            *(float4*)&gl[c * 136 + seg]     = v0;
            *(float4*)&gl[c * 136 + seg + 8] = v1;
        }
        __syncthreads();

#pragma unroll 2
        for (int mt = 0; mt < 8; mt++) {
            // A-frag of phi: row = m-local = col, k = q*4+j (q>=2 -> zero)
            half4v af = zeroh;
            if (q < 2)
                af = *(const half4v*)&phl[(m0 + mt * 16 + col) * 8 + q * 4];
            float4v S = mfma16(af, thB, zero4);
            // S^T[m = m0 + mt*16 + q*4 + r][n = nbase + col]
            half4v P;
            P[0] = (_Float16)__expf(S.x - shift);
            P[1] = (_Float16)__expf(S.y - shift);
            P[2] = (_Float16)__expf(S.z - shift);
            P[3] = (_Float16)__expf(S.w - shift);
            // A-frags of gT: row = c-local = col, k = m-local = q*4+j
            half4v ag0 = *(const half4v*)&gl[col * 136 + mt * 16 + q * 4];
            half4v ag1 = *(const half4v*)&gl[(col + 16) * 136 + mt * 16 + q * 4];
            acc0 = mfma16(ag0, P, acc0);   // O^T c 0-15
            acc1 = mfma16(ag1, P, acc1);   // O^T c 16-31
            accd = mfma16(onesA, P, accd); // row 0 = denominator
        }
    }

    // denominator: accd row 0 lives on lanes 0-15 (q==0), element .x
    float dv = __shfl(accd.x, col);            // den[n] broadcast to all quads
    float sc = gamma_p[0] / dv;                // fold gamma into the scale

    // normalized O^T as B-frags for the w_o MFMA
    half4v B0, B1;
    B0[0] = (_Float16)(acc0.x * sc); B0[1] = (_Float16)(acc0.y * sc);
    B0[2] = (_Float16)(acc0.z * sc); B0[3] = (_Float16)(acc0.w * sc);
    B1[0] = (_Float16)(acc1.x * sc); B1[1] = (_Float16)(acc1.y * sc);
    B1[2] = (_Float16)(acc1.z * sc); B1[3] = (_Float16)(acc1.w * sc);

#pragma unroll
    for (int ct = 0; ct < 4; ct++) {
        // w_o A-frags: row = co-local = col, k = c = half*16 + q*4+j
        const float* wp = w_o + (size_t)(ct * 16 + col) * 32 + q * 4;
        float4 w0 = *(const float4*)wp;           // c 0-15 part
        float4 w1 = *(const float4*)(wp + 16);    // c 16-31 part
        half4v wa, wb;
        wa[0] = (_Float16)w0.x; wa[1] = (_Float16)w0.y;
        wa[2] = (_Float16)w0.z; wa[3] = (_Float16)w0.w;
        wb[0] = (_Float16)w1.x; wb[1] = (_Float16)w1.y;
        wb[2] = (_Float16)w1.z; wb[3] = (_Float16)w1.w;
        float4v D = mfma16(wa, B0, zero4);
        D = mfma16(wb, B1, D);
        // D[co-local = q*4+r][n = col]; out = D + x (gamma already in sc)
#pragma unroll
        for (int r = 0; r < 4; r++) {
            int co = ct * 16 + q * 4 + r;
            size_t idx = ((size_t)b * CC + co) * NN + nbase + col;
            out[idx] = D[r] + x[idx];
        }
    }
}

extern "C" void kernel_launch(void* const* d_in, const int* in_sizes, int n_in,
                              void* d_out, int out_size, void* d_ws, size_t ws_size,
                              hipStream_t stream) {
    const float* x       = (const float*)d_in[0];
    const float* w_theta = (const float*)d_in[1];
    const float* w_phi   = (const float*)d_in[2];
    const float* w_g     = (const float*)d_in[3];
    const float* w_o     = (const float*)d_in[4];
    const float* gamma   = (const float*)d_in[5];
    float* out = (float*)d_out;

    // fp16 workspace: theta [B][N][8], phi [B][M][8], gT [B][32][M] = 2.4 MB
    _Float16* theta_ws = (_Float16*)d_ws;
    _Float16* phi_ws   = theta_ws + (size_t)BB * NN * 8;
    _Float16* gT_ws    = phi_ws   + (size_t)BB * MM * 8;

    proj_kernel<<<dim3(16, BB, 2), 128, 0, stream>>>(
        x, w_theta, w_phi, w_g, theta_ws, phi_ws, gT_ws);

    attn_kernel<<<dim3(NN / 64, BB), 256, 0, stream>>>(
        theta_ws, phi_ws, gT_ws, w_o, gamma, x, out);
}